// Round 1
// baseline (114.350 us; speedup 1.0000x reference)
//
#include <hip/hip_runtime.h>

// SpectralConv2d: B=2,L=8,C=64,H=64,W=33, M1=M2=16
// out[ri, b, l, o, x, y]: complex corner matmuls over c; zero elsewhere.

constexpr int Cc   = 64;
constexpr int Hh   = 64;
constexpr int Ww   = 33;
constexpr int BL   = 16;          // B*L
constexpr int HW   = Hh * Ww;     // 2112
constexpr int PLANE = Cc * HW;    // 135168 (one b,l image stack over c)
constexpr int TOT  = BL * PLANE;  // 2162688 (size of real part of output)
constexpr int WSTR = Cc * 16 * 16; // 16384: o-stride in weight tensor

__global__ __launch_bounds__(256) void spectral_corner_kernel(
    const float* __restrict__ xr, const float* __restrict__ xi,
    const float* __restrict__ wr1, const float* __restrict__ wi1,
    const float* __restrict__ wr2, const float* __restrict__ wi2,
    float* __restrict__ out)
{
    // blockIdx.x in [0,2048): oq(4) | bl(16) | xrow(16) | corner(2)
    const int bid    = blockIdx.x;
    const int oq     = bid & 3;
    const int blidx  = (bid >> 2) & 15;
    const int xrow   = (bid >> 6) & 15;
    const int corner = bid >> 10;

    const int t = threadIdx.x;
    const int y = t & 15;                // fastest: coalesced loads/stores
    const int o = oq * 16 + (t >> 4);

    const float* wr = corner ? wr2 : wr1;
    const float* wi = corner ? wi2 : wi1;
    const int xin = corner ? (48 + xrow) : xrow;   // H row in x and out

    const float* xrp = xr + blidx * PLANE + xin * Ww + y;   // + c*HW
    const float* xip = xi + blidx * PLANE + xin * Ww + y;
    const float* wrp = wr + o * WSTR + xrow * 16 + y;       // + c*256
    const float* wip = wi + o * WSTR + xrow * 16 + y;

    float or_ = 0.f, oi_ = 0.f;
    #pragma unroll 8
    for (int c = 0; c < Cc; ++c) {
        const float a   = xrp[c * HW];
        const float b   = xip[c * HW];
        const float wre = wrp[c * 256];
        const float wim = wip[c * 256];
        or_ = fmaf(a,  wre, or_);
        or_ = fmaf(-b, wim, or_);
        oi_ = fmaf(a,  wim, oi_);
        oi_ = fmaf(b,  wre, oi_);
    }

    const size_t oidx = (size_t)(blidx * Cc + o) * HW + (size_t)xin * Ww + y;
    out[oidx]       = or_;
    out[TOT + oidx] = oi_;
}

extern "C" void kernel_launch(void* const* d_in, const int* in_sizes, int n_in,
                              void* d_out, int out_size, void* d_ws, size_t ws_size,
                              hipStream_t stream) {
    const float* xr  = (const float*)d_in[0];
    const float* xi  = (const float*)d_in[1];
    const float* wr1 = (const float*)d_in[2];
    const float* wi1 = (const float*)d_in[3];
    const float* wr2 = (const float*)d_in[4];
    const float* wi2 = (const float*)d_in[5];
    float* out = (float*)d_out;

    // Zero the whole output (corners get overwritten by the compute kernel).
    hipMemsetAsync(d_out, 0, (size_t)out_size * sizeof(float), stream);

    spectral_corner_kernel<<<2048, 256, 0, stream>>>(xr, xi, wr1, wi1, wr2, wi2, out);
}

// Round 2
// 108.835 us; speedup vs baseline: 1.0507x; 1.0507x over previous
//
#include <hip/hip_runtime.h>

// SpectralConv2d: B=2,L=8,C=64,H=64,W=33, M1=M2=16
// Single fused kernel: corner complex matmuls + zero fill, each output
// element written exactly once (no memset, no double-write, one launch).

constexpr int Cc    = 64;
constexpr int Hh    = 64;
constexpr int Ww    = 33;
constexpr int BL    = 16;           // B*L
constexpr int HW    = Hh * Ww;      // 2112
constexpr int PLANE = Cc * HW;      // 135168
constexpr int TOT   = BL * PLANE;   // 2162688 (elements in real half)
constexpr int WSTR  = Cc * 16 * 16; // 16384: o-stride in weight tensor

__global__ __launch_bounds__(256) void spectral_fused_kernel(
    const float* __restrict__ xr, const float* __restrict__ xi,
    const float* __restrict__ wr1, const float* __restrict__ wi1,
    const float* __restrict__ wr2, const float* __restrict__ wi2,
    float* __restrict__ out)
{
    const int bid = blockIdx.x;
    const int t   = threadIdx.x;

    if (bid < 2048) {
        // ---- compute blocks: oq(4) | bl(16) | xrow(16) | corner(2) ----
        const int oq     = bid & 3;
        const int blidx  = (bid >> 2) & 15;
        const int xrow   = (bid >> 6) & 15;
        const int corner = bid >> 10;

        const int y = t & 15;               // fastest: coalesced
        const int o = oq * 16 + (t >> 4);

        const float* wr = corner ? wr2 : wr1;
        const float* wi = corner ? wi2 : wi1;
        const int xin = corner ? (48 + xrow) : xrow;

        const float* xrp = xr + blidx * PLANE + xin * Ww + y;   // + c*HW
        const float* xip = xi + blidx * PLANE + xin * Ww + y;
        const float* wrp = wr + o * WSTR + xrow * 16 + y;       // + c*256
        const float* wip = wi + o * WSTR + xrow * 16 + y;

        float or_ = 0.f, oi_ = 0.f;
        #pragma unroll 8
        for (int c = 0; c < Cc; ++c) {
            const float a   = xrp[c * HW];
            const float b   = xip[c * HW];
            const float wre = wrp[c * 256];
            const float wim = wip[c * 256];
            or_ = fmaf(a,  wre, or_);
            or_ = fmaf(-b, wim, or_);
            oi_ = fmaf(a,  wim, oi_);
            oi_ = fmaf(b,  wre, oi_);
        }

        const size_t oidx = (size_t)(blidx * Cc + o) * HW + (size_t)xin * Ww + y;
        out[oidx]       = or_;
        out[TOT + oidx] = oi_;

        // ---- zero the y in [16,33) tails of this block's 16 o-rows, both ri ----
        // 544 = 2(ri) * 16(o) * 17(y) elements; threads cover k = t, t+256, t+512.
        const size_t rowbase0 = (size_t)(blidx * Cc + oq * 16) * HW + (size_t)xin * Ww;
        #pragma unroll
        for (int k = t; k < 544; k += 256) {
            const int ri  = k >= 272;
            const int rem = ri ? (k - 272) : k;
            const int ol  = rem / 17;        // local o within this block's 16
            const int yy  = 16 + rem % 17;
            const size_t idx = rowbase0 + (size_t)ol * HW + yy + (ri ? (size_t)TOT : 0);
            out[idx] = 0.f;
        }
    } else {
        // ---- zero blocks: one per (ri, bl, o) plane, middle rows x in [16,48) ----
        // 1056 contiguous floats starting at plane*2112 + 528 -> 264 float4.
        const int p = bid - 2048;            // [0, 2048)
        const int ri = p >> 10;
        const int plane = p & 1023;          // bl*64 + o
        float4* dst = (float4*)(out + (size_t)ri * TOT + (size_t)plane * HW + 528);
        const float4 z = make_float4(0.f, 0.f, 0.f, 0.f);
        dst[t] = z;
        if (t < 8) dst[256 + t] = z;         // 264 = 256 + 8
    }
}

extern "C" void kernel_launch(void* const* d_in, const int* in_sizes, int n_in,
                              void* d_out, int out_size, void* d_ws, size_t ws_size,
                              hipStream_t stream) {
    const float* xr  = (const float*)d_in[0];
    const float* xi  = (const float*)d_in[1];
    const float* wr1 = (const float*)d_in[2];
    const float* wi1 = (const float*)d_in[3];
    const float* wr2 = (const float*)d_in[4];
    const float* wi2 = (const float*)d_in[5];
    float* out = (float*)d_out;

    spectral_fused_kernel<<<4096, 256, 0, stream>>>(xr, xi, wr1, wi1, wr2, wi2, out);
}